// Round 3
// baseline (4239.679 us; speedup 1.0000x reference)
//
#include <hip/hip_runtime.h>
#include <hip/hip_bf16.h>
#include <cstdio>

typedef __hip_bfloat16 bf16;
typedef __attribute__((ext_vector_type(8))) short s16x8;
typedef __attribute__((ext_vector_type(4))) float f32x4;

// Problem constants
#define TT 55
#define BB 512
#define CC 512
#define DD 512
#define KK 64
#define LDH ((long)TT*1536)

typedef const __attribute__((address_space(1))) unsigned int gu32;
typedef __attribute__((address_space(3))) unsigned int lu32;
__device__ __forceinline__ void gload16(const void* g, void* l) {
  __builtin_amdgcn_global_load_lds((gu32*)g, (lu32*)l, 16, 0, 0);
}

struct Seg {
  float* dst;          // destination base
  long   ldd;          // row stride (elements)
  int    col_begin;    // inclusive (GEMM N space), 64-aligned, sorted asc
  int    mode;         // 0 = store (+bias), 1 = atomicAdd
  const float* bias;   // indexed by (col - col_begin), may be null
};
struct SegList { Seg s[8]; int n; };

struct GDesc {
  const bf16* A; const bf16* B;
  long lda, ldb;
  int mtiles, ntiles, tile_beg, order;  // order: 0 = nt-fast (stream A), 1 = mt-fast (stream B)
  SegList segs;
};
struct GArgs { GDesc g[4]; int ng; int K; int total; int chunk; };

// ---------------- batched GEMM: C[seg] (+)= A[MxK] * B^T[NxK], bf16 in, fp32 out
// 128x128 tile, BK=64, 4 waves (2x2), global_load_lds staging, XCD chunk-swizzle.
__global__ __launch_bounds__(256) void gemm_batched(GArgs args)
{
  __shared__ __align__(16) bf16 As[128][64];
  __shared__ __align__(16) bf16 Bs[128][64];

  // XCD-aware: bid%8 ~ XCD; give each XCD a contiguous tile chunk.
  int tile = (int)(blockIdx.x & 7) * args.chunk + (int)(blockIdx.x >> 3);
  if (tile >= args.total) return;

  int gi = 0;
  if (args.ng > 1 && tile >= args.g[1].tile_beg) gi = 1;
  if (args.ng > 2 && tile >= args.g[2].tile_beg) gi = 2;
  if (args.ng > 3 && tile >= args.g[3].tile_beg) gi = 3;
  const GDesc& g = args.g[gi];
  const int local = tile - g.tile_beg;
  int mt, nt;
  if (g.order) { mt = local % g.mtiles; nt = local / g.mtiles; }
  else         { nt = local % g.ntiles; mt = local / g.ntiles; }

  const int tid  = threadIdx.x;
  const int wave = tid >> 6, lane = tid & 63;
  const int q = lane >> 4, mm = lane & 15;
  const int wm = wave >> 1, wn = wave & 1;
  const long m0 = (long)mt * 128;
  const long n0 = (long)nt * 128;

  const bf16* Ab = g.A + m0 * g.lda;
  const bf16* Bb = g.B + n0 * g.ldb;
  const long lda = g.lda, ldb = g.ldb;
  const int l8 = lane >> 3;        // row within 8-row staging group
  const int c8 = (lane & 7) << 3;  // element col within 64-wide row

  f32x4 acc[4][4] = {};

  for (int k0 = 0; k0 < args.K; k0 += 64) {
    // stage A/B tiles (128x64 bf16 each) direct to LDS; wave-uniform LDS base,
    // HW scatters lane*16B -> row-major [128][64] (rows of 128B).
#pragma unroll
    for (int p = 0; p < 4; ++p) {
      int r = p*32 + wave*8;
      gload16(Ab + (long)(r + l8)*lda + k0 + c8, &As[r][0]);
      gload16(Bb + (long)(r + l8)*ldb + k0 + c8, &Bs[r][0]);
    }
    __syncthreads();
#pragma unroll
    for (int kk = 0; kk < 64; kk += 32) {
      s16x8 av[4], bv[4];
#pragma unroll
      for (int i = 0; i < 4; ++i) av[i] = *(const s16x8*)&As[wm*64 + i*16 + mm][kk + q*8];
#pragma unroll
      for (int j = 0; j < 4; ++j) bv[j] = *(const s16x8*)&Bs[wn*64 + j*16 + mm][kk + q*8];
#pragma unroll
      for (int i = 0; i < 4; ++i)
#pragma unroll
        for (int j = 0; j < 4; ++j)
          acc[i][j] = __builtin_amdgcn_mfma_f32_16x16x32_bf16(av[i], bv[j], acc[i][j], 0,0,0);
    }
    __syncthreads();
  }

  // epilogue: segment lookup per 16-col group (boundaries are 64-aligned)
#pragma unroll
  for (int j = 0; j < 4; ++j) {
    int colbase = (int)n0 + wn*64 + j*16;
    Seg sg = g.segs.s[0];
    for (int i = 1; i < g.segs.n; ++i)
      if (colbase >= g.segs.s[i].col_begin) sg = g.segs.s[i];
    int dcol = colbase + mm - sg.col_begin;
    float bv = sg.bias ? sg.bias[dcol] : 0.0f;
#pragma unroll
    for (int i = 0; i < 4; ++i) {
      f32x4 a = acc[i][j];
#pragma unroll
      for (int r = 0; r < 4; ++r) {
        long row = m0 + wm*64 + i*16 + q*4 + r;  // C/D: col=lane&15, row=q*4+reg
        float* p = sg.dst + row * sg.ldd + dcol;
        if (sg.mode) atomicAdd(p, a[r]);
        else         *p = a[r] + bv;
      }
    }
  }
}

// ---------------- batched cell update: up to 3 independent (step,layer) cells
struct CellDesc {
  const float* gate;   // [512][2048]
  const float* gr;     // [512][64]
  const float* u0;     // may be null
  const float* u1;     // may be null
  float* c;            // [512][512]
  float* d;            // [512][64]
  bf16*  hout;         // row stride LDH
};
struct CArgs { CellDesc e[3]; int n; };

__device__ inline float sigm(float x){ return 1.0f/(1.0f + __expf(-x)); }

__global__ __launch_bounds__(256) void cell_batched(CArgs a, const float* __restrict__ wd)
{
  const CellDesc e = a.e[blockIdx.y];
  const int tid = threadIdx.x;
  const int r0 = blockIdx.x * 8;   // 8 batch rows per block, grid.x = 64
  __shared__ float dn[8][64];

  for (int i = tid; i < 512; i += 256) {
    int r = i >> 6, k = i & 63;
    long idx = (long)(r0 + r)*64 + k;
    float gv = e.gr[idx];
    if (e.u0) gv += (1.0f/3.0f)*e.u0[idx];
    if (e.u1) gv += (1.0f/3.0f)*e.u1[idx];
    float rr = sigm(gv);
    float dv = rr * e.d[idx];
    e.d[idx] = dv;
    dn[r][k] = dv;
  }
  __syncthreads();

  float accv[2][8] = {};
  for (int k = 0; k < 64; ++k) {
    float w0 = wd[k*512 + tid];
    float w1 = wd[k*512 + tid + 256];
#pragma unroll
    for (int r = 0; r < 8; ++r) {
      float dv = dn[r][k];
      accv[0][r] += dv * w0;
      accv[1][r] += dv * w1;
    }
  }

#pragma unroll
  for (int half = 0; half < 2; ++half) {
    int n = tid + half*256;
#pragma unroll
    for (int r = 0; r < 8; ++r) {
      long row = r0 + r;
      const float* gg = e.gate + row*2048;
      float fv = sigm(gg[n]);
      float iv = sigm(gg[512 + n]);
      float ov = sigm(gg[1024 + n]);
      float cb = tanhf(gg[1536 + n]);
      float cv = fv * e.c[row*512 + n] + iv * cb + tanhf(accv[half][r]);
      e.c[row*512 + n] = cv;
      e.hout[row*LDH + n] = __float2bfloat16(ov * tanhf(cv));
    }
  }
}

// ---------------- setup kernels
__global__ void k_tpose(const float* __restrict__ src, long srow,
                        bf16* __restrict__ dst, int K, long total)
{
  long idx = (long)blockIdx.x * 256 + threadIdx.x;
  if (idx >= total) return;
  long n = idx / K;
  long k = idx - n * K;
  dst[idx] = __float2bfloat16(src[k * srow + n]);
}

__global__ void k_xconv(const float* __restrict__ x, bf16* __restrict__ xb)
{
  long i = (long)blockIdx.x * 256 + threadIdx.x;
  if (i >= (long)TT*BB*CC) return;
  int cc = (int)(i & 511);
  long r = i >> 9;
  int t = (int)(r / BB), b = (int)(r - (long)t*BB);
  xb[i] = __float2bfloat16(x[((long)b*TT + t)*CC + cc]);
}

__global__ void k_bias(const float* b0,const float* b1,const float* b2,
                       const float* b3,const float* b4,const float* b5,
                       float* out)
{
  int i = blockIdx.x*256 + threadIdx.x;
  if (i < 2048)      out[i] = b0[i] + b1[i];
  else if (i < 4096) out[i] = b2[i-2048] + b3[i-2048];
  else if (i < 6144) out[i] = b4[i-4096] + b5[i-4096];
}

__global__ void k_dinit(const float* __restrict__ keys, float* __restrict__ d)
{
  int i = blockIdx.x*256 + threadIdx.x;
  if (i < 3*BB*KK) d[i] = keys[i % (BB*KK)];
}

// ---------------- host
extern "C" void kernel_launch(void* const* d_in, const int* in_sizes, int n_in,
                              void* d_out, int out_size, void* d_ws, size_t ws_size,
                              hipStream_t stream)
{
  const float* inputs    = (const float*)d_in[0];
  const float* init_keys = (const float*)d_in[1];
  const float* wx_w[3] = {(const float*)d_in[2],  (const float*)d_in[8],  (const float*)d_in[14]};
  const float* wx_b[3] = {(const float*)d_in[3],  (const float*)d_in[9],  (const float*)d_in[15]};
  const float* wh_w[3] = {(const float*)d_in[4],  (const float*)d_in[10], (const float*)d_in[16]};
  const float* wh_b[3] = {(const float*)d_in[5],  (const float*)d_in[11], (const float*)d_in[17]};
  const float* wr_w[3] = {(const float*)d_in[6],  (const float*)d_in[12], (const float*)d_in[18]};
  const float* wl_w[3] = {(const float*)d_in[7],  (const float*)d_in[13], (const float*)d_in[19]};
  const float* wd_w   = (const float*)d_in[20];
  const float* proj_w = (const float*)d_in[21];
  const float* proj_b = (const float*)d_in[22];
  float* out = (float*)d_out;

  char* wsp = (char*)d_ws;
  size_t used = 0;
  auto alloc = [&](size_t bytes) {
    char* p = wsp + used;
    used += (bytes + 255) & ~(size_t)255;
    return p;
  };
  // padded N: BXT/BG0T 6336->6400, BG1T 4224->4352
  bf16* xb    = (bf16*)alloc((size_t)TT*BB*CC*2);        // [t][b][c]
  bf16* BXT   = (bf16*)alloc((size_t)6400*512*2);        // x-driven  B^T (padded)
  bf16* BG0T  = (bf16*)alloc((size_t)6400*512*2);        // h0-driven B^T (padded)
  bf16* BG1T  = (bf16*)alloc((size_t)4352*512*2);        // h1-driven B^T (padded)
  bf16* BG2T  = (bf16*)alloc((size_t)2048*512*2);        // h2-driven B^T
  bf16* projT = (bf16*)alloc((size_t)512*1536*2);
  bf16* Hall  = (bf16*)alloc((size_t)BB*TT*1536*2);      // [b][t][3*512]
  float* accg = (float*)alloc((size_t)4*3*BB*2048*4);    // [slot][l][b][2048]
  float* accr = (float*)alloc((size_t)4*3*BB*64*4);      // [slot][l][b][64]
  float* ubuf = (float*)alloc((size_t)4*2*BB*64*4);      // [slot][j][b][64]
  float* cbuf = (float*)alloc((size_t)3*BB*DD*4);
  float* dbuf = (float*)alloc((size_t)3*BB*KK*4);
  float* biasg= (float*)alloc((size_t)3*2048*4);
  float* dump = (float*)alloc((size_t)BB*128*4);         // pad-column sink
  if (used > ws_size) { fprintf(stderr, "ws too small: need %zu have %zu\n", used, ws_size); return; }

  const long SZG = (long)BB*2048;
  const long SZR = (long)BB*64;

  auto slotg = [&](int s, int l){ return accg + (long)((s&3)*3+l)*SZG; };
  auto slotr = [&](int s, int l){ return accr + (long)((s&3)*3+l)*SZR; };
  auto slotu = [&](int s, int j){ return ubuf + (long)((s&3)*2+j)*SZR; };

  // ---- setup
  {
    long tot = (long)TT*BB*CC;
    k_xconv<<<dim3((tot + 255)/256), 256, 0, stream>>>(inputs, xb);
  }
  // zero padded weight buffers first (pad rows must be 0; ws is poisoned 0xAA)
  hipMemsetAsync(BXT,  0, (size_t)6400*512*2, stream);
  hipMemsetAsync(BG0T, 0, (size_t)6400*512*2, stream);
  hipMemsetAsync(BG1T, 0, (size_t)4352*512*2, stream);

  auto tp = [&](const float* src, long row_off, long srow, bf16* dstbase, long colbase, int N, int K){
    long total = (long)N*K;
    k_tpose<<<dim3((total + 255)/256), 256, 0, stream>>>(src + row_off*srow, srow, dstbase + colbase*K, K, total);
  };
  // BXT cols: [Wx0|Wr0|Wx1|Wr1|Wx2|Wr2|pad]
  tp(wx_w[0],0,2048, BXT,0,2048,512);   tp(wr_w[0],0,64, BXT,2048,64,512);
  tp(wx_w[1],0,2048, BXT,2112,2048,512);tp(wr_w[1],0,64, BXT,4160,64,512);
  tp(wx_w[2],0,2048, BXT,4224,2048,512);tp(wr_w[2],0,64, BXT,6272,64,512);
  // BG0T cols: [Wx1.h0|Wr1.h0|Wx2.h0|Wr2.h0|Wh0|Wl0|pad]
  tp(wx_w[1],512,2048, BG0T,0,2048,512);   tp(wr_w[1],512,64, BG0T,2048,64,512);
  tp(wx_w[2],512,2048, BG0T,2112,2048,512);tp(wr_w[2],512,64, BG0T,4160,64,512);
  tp(wh_w[0],0,2048,   BG0T,4224,2048,512);tp(wl_w[0],0,64,   BG0T,6272,64,512);
  // BG1T cols: [Wx2.h1|Wr2.h1|Wh1|Wl1|pad]
  tp(wx_w[2],1024,2048, BG1T,0,2048,512);  tp(wr_w[2],1024,64, BG1T,2048,64,512);
  tp(wh_w[1],0,2048,    BG1T,2112,2048,512);tp(wl_w[1],0,64,   BG1T,4160,64,512);
  // BG2T: [Wh2]
  tp(wh_w[2],0,2048, BG2T,0,2048,512);
  // projT
  tp(proj_w,0,512, projT,0,512,1536);

  k_bias<<<dim3(24),256,0,stream>>>(wx_b[0],wh_b[0],wx_b[1],wh_b[1],wx_b[2],wh_b[2], biasg);
  hipMemsetAsync(ubuf, 0, (size_t)4*2*BB*64*4, stream);
  hipMemsetAsync(cbuf, 0, (size_t)3*BB*DD*4, stream);
  k_dinit<<<dim3((3*BB*KK + 255)/256),256,0,stream>>>(init_keys, dbuf);

  // ---- pipelined recurrence: A(t) = {E0(t),E1(t-1),E2(t-2)}, B(t) = {I(t+2),G0(t),G1(t-1),G2(t-2)}
  for (int t = -2; t <= TT + 1; ++t) {
    // ----- A phase
    CArgs ca{}; ca.n = 0;
    auto addE = [&](int s, int l){
      CellDesc& e = ca.e[ca.n++];
      e.gate = slotg(s,l); e.gr = slotr(s,l);
      e.u0 = (l>=1) ? slotu(s-1,0) : nullptr;
      e.u1 = (l>=2) ? slotu(s-1,1) : nullptr;
      e.c = cbuf + (long)l*BB*DD; e.d = dbuf + (long)l*BB*KK;
      e.hout = Hall + (long)s*1536 + (long)l*512;
    };
    if (t   >= 0 && t   < TT) addE(t,   0);
    if (t-1 >= 0 && t-1 < TT) addE(t-1, 1);
    if (t-2 >= 0 && t-2 < TT) addE(t-2, 2);
    if (ca.n)
      cell_batched<<<dim3(64, ca.n), 256, 0, stream>>>(ca, wd_w);

    // ----- B phase
    GArgs ga{}; ga.ng = 0; ga.K = 512;
    int cursor = 0;
    auto addG = [&](const bf16* A, long lda, const bf16* Bm, int Npad, SegList sl){
      GDesc& g = ga.g[ga.ng++];
      g.A = A; g.lda = lda; g.B = Bm; g.ldb = 512;
      g.mtiles = 4; g.ntiles = Npad/128; g.tile_beg = cursor; g.order = 1;
      cursor += g.mtiles * g.ntiles;
      g.segs = sl;
    };
    if (t+2 >= 0 && t+2 < TT) {  // I(t+2)
      int s = t+2;
      SegList sl{}; sl.n = 7;
      sl.s[0] = { slotg(s,0), 2048,    0, 0, biasg + 0    };
      sl.s[1] = { slotr(s,0),   64, 2048, 0, nullptr      };
      sl.s[2] = { slotg(s,1), 2048, 2112, 0, biasg + 2048 };
      sl.s[3] = { slotr(s,1),   64, 4160, 0, nullptr      };
      sl.s[4] = { slotg(s,2), 2048, 4224, 0, biasg + 4096 };
      sl.s[5] = { slotr(s,2),   64, 6272, 0, nullptr      };
      sl.s[6] = { dump,        128, 6336, 0, nullptr      };
      addG(xb + (long)s*BB*CC, 512, BXT, 6400, sl);
    }
    if (t >= 0 && t < TT) {      // G0(t)
      int s = t;
      SegList sl{}; sl.n = 7;
      sl.s[0] = { slotg(s,1),   2048,    0, 1, nullptr };
      sl.s[1] = { slotr(s,1),     64, 2048, 1, nullptr };
      sl.s[2] = { slotg(s,2),   2048, 2112, 1, nullptr };
      sl.s[3] = { slotr(s,2),     64, 4160, 1, nullptr };
      sl.s[4] = { slotg(s+1,0), 2048, 4224, 1, nullptr };  // Wh0 -> gate0(t+1)
      sl.s[5] = { slotu(s,0),     64, 6272, 0, nullptr };  // u0 = h0@Wl0
      sl.s[6] = { dump,          128, 6336, 0, nullptr };
      addG(Hall + (long)s*1536, LDH, BG0T, 6400, sl);
    }
    if (t-1 >= 0 && t-1 < TT) {  // G1(t-1)
      int s = t-1;
      SegList sl{}; sl.n = 5;
      sl.s[0] = { slotg(s,2),   2048,    0, 1, nullptr };
      sl.s[1] = { slotr(s,2),     64, 2048, 1, nullptr };
      sl.s[2] = { slotg(s+1,1), 2048, 2112, 1, nullptr };  // Wh1 -> gate1(s+1)
      sl.s[3] = { slotu(s,1),     64, 4160, 0, nullptr };  // u1 = h1@Wl1
      sl.s[4] = { dump,          128, 4224, 0, nullptr };
      addG(Hall + (long)s*1536 + 512, LDH, BG1T, 4352, sl);
    }
    if (t-2 >= 0 && t-2 <= TT-2) {  // G2(t-2)
      int s = t-2;
      SegList sl{}; sl.n = 1;
      sl.s[0] = { slotg(s+1,2), 2048, 0, 1, nullptr };     // Wh2 -> gate2(s+1)
      addG(Hall + (long)s*1536 + 1024, LDH, BG2T, 2048, sl);
    }
    if (cursor) {
      ga.total = cursor; ga.chunk = (cursor + 7) / 8;
      gemm_batched<<<dim3(ga.chunk * 8), 256, 0, stream>>>(ga);
    }
  }

  // ---- projection: out[b][t][:] = Hall[b][t][:] @ proj + proj_b
  {
    GArgs ga{}; ga.ng = 1; ga.K = 1536;
    GDesc& g = ga.g[0];
    g.A = Hall; g.lda = 1536; g.B = projT; g.ldb = 1536;
    g.mtiles = (BB*TT)/128; g.ntiles = 512/128; g.tile_beg = 0; g.order = 0;
    g.segs.n = 1;
    g.segs.s[0] = { out, 512, 0, 0, proj_b };
    ga.total = g.mtiles * g.ntiles; ga.chunk = (ga.total + 7) / 8;
    gemm_batched<<<dim3(ga.chunk * 8), 256, 0, stream>>>(ga);
  }
}

// Round 4
// 3389.257 us; speedup vs baseline: 1.2509x; 1.2509x over previous
//
#include <hip/hip_runtime.h>
#include <hip/hip_bf16.h>
#include <cstdio>

typedef __hip_bfloat16 bf16;
typedef __attribute__((ext_vector_type(8))) short s16x8;
typedef __attribute__((ext_vector_type(4))) float f32x4;

// Problem constants
#define TT 55
#define BB 512
#define CC 512
#define DD 512
#define KK 64
#define LDH ((long)TT*1536)

typedef const __attribute__((address_space(1))) unsigned int gu32;
typedef __attribute__((address_space(3))) unsigned int lu32;
__device__ __forceinline__ void gload16(const void* g, void* l) {
  __builtin_amdgcn_global_load_lds((gu32*)g, (lu32*)l, 16, 0, 0);
}

struct Seg {
  float* dst;          // destination base
  long   ldd;          // row stride (elements)
  int    col_begin;    // inclusive (GEMM N space), 64-aligned, sorted asc
  int    mode;         // 0 = store (+bias), 1 = plain +=  (single writer per launch!)
  const float* bias;   // indexed by (col - col_begin), may be null
};
struct SegList { Seg s[8]; int n; };

struct GDesc {
  const bf16* A; const bf16* B;
  long lda, ldb;
  int mtiles, ntiles, tile_beg, order;  // order: 0 = nt-fast (stream A), 1 = mt-fast (stream B)
  SegList segs;
};
struct GArgs { GDesc g[4]; int ng; int K; int total; int chunk; };

// ---------------- batched GEMM: C[seg] (+)= A[MxK] * B^T[NxK], bf16 in, fp32 out
// 64x128 tile (MxN), BK=64, 4 waves (2x2 of 32x64), global_load_lds staging,
// XCD chunk-swizzle. No atomics: every segment has a single writer per launch.
__global__ __launch_bounds__(256) void gemm_batched(GArgs args)
{
  __shared__ __align__(16) bf16 As[64][64];    // 8 KB
  __shared__ __align__(16) bf16 Bs[128][64];   // 16 KB

  // XCD-aware: bid%8 ~ XCD; give each XCD a contiguous tile chunk.
  int tile = (int)(blockIdx.x & 7) * args.chunk + (int)(blockIdx.x >> 3);
  if (tile >= args.total) return;

  int gi = 0;
  if (args.ng > 1 && tile >= args.g[1].tile_beg) gi = 1;
  if (args.ng > 2 && tile >= args.g[2].tile_beg) gi = 2;
  if (args.ng > 3 && tile >= args.g[3].tile_beg) gi = 3;
  const GDesc& g = args.g[gi];
  const int local = tile - g.tile_beg;
  int mt, nt;
  if (g.order) { mt = local % g.mtiles; nt = local / g.mtiles; }
  else         { nt = local % g.ntiles; mt = local / g.ntiles; }

  const int tid  = threadIdx.x;
  const int wave = tid >> 6, lane = tid & 63;
  const int q = lane >> 4, mm = lane & 15;
  const int wm = wave >> 1, wn = wave & 1;
  const long m0 = (long)mt * 64;
  const long n0 = (long)nt * 128;

  const bf16* Ab = g.A + m0 * g.lda;
  const bf16* Bb = g.B + n0 * g.ldb;
  const long lda = g.lda, ldb = g.ldb;
  const int l8 = lane >> 3;        // row within 8-row staging group
  const int c8 = (lane & 7) << 3;  // element col within 64-wide row

  f32x4 acc[2][4] = {};

  for (int k0 = 0; k0 < args.K; k0 += 64) {
    // A: 64x64 (2 issues of 32 rows), B: 128x64 (4 issues of 32 rows)
#pragma unroll
    for (int p = 0; p < 2; ++p) {
      int r = p*32 + wave*8;
      gload16(Ab + (long)(r + l8)*lda + k0 + c8, &As[r][0]);
    }
#pragma unroll
    for (int p = 0; p < 4; ++p) {
      int r = p*32 + wave*8;
      gload16(Bb + (long)(r + l8)*ldb + k0 + c8, &Bs[r][0]);
    }
    __syncthreads();
#pragma unroll
    for (int kk = 0; kk < 64; kk += 32) {
      s16x8 av[2], bv[4];
#pragma unroll
      for (int i = 0; i < 2; ++i) av[i] = *(const s16x8*)&As[wm*32 + i*16 + mm][kk + q*8];
#pragma unroll
      for (int j = 0; j < 4; ++j) bv[j] = *(const s16x8*)&Bs[wn*64 + j*16 + mm][kk + q*8];
#pragma unroll
      for (int i = 0; i < 2; ++i)
#pragma unroll
        for (int j = 0; j < 4; ++j)
          acc[i][j] = __builtin_amdgcn_mfma_f32_16x16x32_bf16(av[i], bv[j], acc[i][j], 0,0,0);
    }
    __syncthreads();
  }

  // epilogue: segment lookup per 16-col group (boundaries are 64-aligned)
#pragma unroll
  for (int j = 0; j < 4; ++j) {
    int colbase = (int)n0 + wn*64 + j*16;
    Seg sg = g.segs.s[0];
    for (int i = 1; i < g.segs.n; ++i)
      if (colbase >= g.segs.s[i].col_begin) sg = g.segs.s[i];
    int dcol = colbase + mm - sg.col_begin;
    float bv = sg.bias ? sg.bias[dcol] : 0.0f;
#pragma unroll
    for (int i = 0; i < 2; ++i) {
      f32x4 a = acc[i][j];
#pragma unroll
      for (int r = 0; r < 4; ++r) {
        long row = m0 + wm*32 + i*16 + q*4 + r;  // C/D: col=lane&15, row=q*4+reg
        float* p = sg.dst + row * sg.ldd + dcol;
        if (sg.mode) *p += a[r];
        else         *p = a[r] + bv;
      }
    }
  }
}

// ---------------- batched cell update: up to 3 independent (step,layer) cells
struct CellDesc {
  const float* gate;   // [512][2048] main gate accum
  const float* gate2;  // [512][2048] extra addend (whb ring), may be null
  const float* gr;     // [512][64]
  const float* u0;     // may be null
  const float* u1;     // may be null
  float* c;            // [512][512]
  float* d;            // [512][64]
  bf16*  hout;         // row stride LDH
};
struct CArgs { CellDesc e[3]; int n; };

__device__ inline float sigm(float x){ return 1.0f/(1.0f + __expf(-x)); }

__global__ __launch_bounds__(256) void cell_batched(CArgs a, const float* __restrict__ wd)
{
  const CellDesc e = a.e[blockIdx.y];
  const int tid = threadIdx.x;
  const int r0 = blockIdx.x * 8;   // 8 batch rows per block, grid.x = 64
  __shared__ float dn[8][64];

  for (int i = tid; i < 512; i += 256) {
    int r = i >> 6, k = i & 63;
    long idx = (long)(r0 + r)*64 + k;
    float gv = e.gr[idx];
    if (e.u0) gv += (1.0f/3.0f)*e.u0[idx];
    if (e.u1) gv += (1.0f/3.0f)*e.u1[idx];
    float rr = sigm(gv);
    float dv = rr * e.d[idx];
    e.d[idx] = dv;
    dn[r][k] = dv;
  }
  __syncthreads();

  float accv[2][8] = {};
  for (int k = 0; k < 64; ++k) {
    float w0 = wd[k*512 + tid];
    float w1 = wd[k*512 + tid + 256];
#pragma unroll
    for (int r = 0; r < 8; ++r) {
      float dv = dn[r][k];
      accv[0][r] += dv * w0;
      accv[1][r] += dv * w1;
    }
  }

#pragma unroll
  for (int half = 0; half < 2; ++half) {
    int n = tid + half*256;
#pragma unroll
    for (int r = 0; r < 8; ++r) {
      long row = r0 + r;
      const float* gg = e.gate + row*2048;
      const float* g2 = e.gate2 ? e.gate2 + row*2048 : nullptr;
      float fv = gg[n]        + (g2 ? g2[n]        : 0.0f);
      float iv = gg[512 + n]  + (g2 ? g2[512 + n]  : 0.0f);
      float ov = gg[1024 + n] + (g2 ? g2[1024 + n] : 0.0f);
      float cb = gg[1536 + n] + (g2 ? g2[1536 + n] : 0.0f);
      fv = sigm(fv); iv = sigm(iv); ov = sigm(ov); cb = tanhf(cb);
      float cv = fv * e.c[row*512 + n] + iv * cb + tanhf(accv[half][r]);
      e.c[row*512 + n] = cv;
      e.hout[row*LDH + n] = __float2bfloat16(ov * tanhf(cv));
    }
  }
}

// ---------------- setup kernels
__global__ void k_tpose(const float* __restrict__ src, long srow,
                        bf16* __restrict__ dst, int K, long total)
{
  long idx = (long)blockIdx.x * 256 + threadIdx.x;
  if (idx >= total) return;
  long n = idx / K;
  long k = idx - n * K;
  dst[idx] = __float2bfloat16(src[k * srow + n]);
}

__global__ void k_xconv(const float* __restrict__ x, bf16* __restrict__ xb)
{
  long i = (long)blockIdx.x * 256 + threadIdx.x;
  if (i >= (long)TT*BB*CC) return;
  int cc = (int)(i & 511);
  long r = i >> 9;
  int t = (int)(r / BB), b = (int)(r - (long)t*BB);
  xb[i] = __float2bfloat16(x[((long)b*TT + t)*CC + cc]);
}

__global__ void k_bias(const float* b0,const float* b1,const float* b2,
                       const float* b3,const float* b4,const float* b5,
                       float* out)
{
  int i = blockIdx.x*256 + threadIdx.x;
  if (i < 2048)      out[i] = b0[i] + b1[i];
  else if (i < 4096) out[i] = b2[i-2048] + b3[i-2048];
  else if (i < 6144) out[i] = b4[i-4096] + b5[i-4096];
}

__global__ void k_dinit(const float* __restrict__ keys, float* __restrict__ d)
{
  int i = blockIdx.x*256 + threadIdx.x;
  if (i < 3*BB*KK) d[i] = keys[i % (BB*KK)];
}

// ---------------- host
extern "C" void kernel_launch(void* const* d_in, const int* in_sizes, int n_in,
                              void* d_out, int out_size, void* d_ws, size_t ws_size,
                              hipStream_t stream)
{
  const float* inputs    = (const float*)d_in[0];
  const float* init_keys = (const float*)d_in[1];
  const float* wx_w[3] = {(const float*)d_in[2],  (const float*)d_in[8],  (const float*)d_in[14]};
  const float* wx_b[3] = {(const float*)d_in[3],  (const float*)d_in[9],  (const float*)d_in[15]};
  const float* wh_w[3] = {(const float*)d_in[4],  (const float*)d_in[10], (const float*)d_in[16]};
  const float* wh_b[3] = {(const float*)d_in[5],  (const float*)d_in[11], (const float*)d_in[17]};
  const float* wr_w[3] = {(const float*)d_in[6],  (const float*)d_in[12], (const float*)d_in[18]};
  const float* wl_w[3] = {(const float*)d_in[7],  (const float*)d_in[13], (const float*)d_in[19]};
  const float* wd_w   = (const float*)d_in[20];
  const float* proj_w = (const float*)d_in[21];
  const float* proj_b = (const float*)d_in[22];
  float* out = (float*)d_out;

  char* wsp = (char*)d_ws;
  size_t used = 0;
  auto alloc = [&](size_t bytes) {
    char* p = wsp + used;
    used += (bytes + 255) & ~(size_t)255;
    return p;
  };
  // padded N: BXT/BG0T 6336->6400, BG1T 4224->4352
  bf16* xb    = (bf16*)alloc((size_t)TT*BB*CC*2);        // [t][b][c]
  bf16* BXT   = (bf16*)alloc((size_t)6400*512*2);        // x-driven  B^T (padded)
  bf16* BG0T  = (bf16*)alloc((size_t)6400*512*2);        // h0-driven B^T (padded)
  bf16* BG1T  = (bf16*)alloc((size_t)4352*512*2);        // h1-driven B^T (padded)
  bf16* BG2T  = (bf16*)alloc((size_t)2048*512*2);        // h2-driven B^T
  bf16* projT = (bf16*)alloc((size_t)512*1536*2);
  bf16* Hall  = (bf16*)alloc((size_t)BB*TT*1536*2);      // [b][t][3*512]
  float* accg = (float*)alloc((size_t)4*3*BB*2048*4);    // [slot][l][b][2048]
  float* accr = (float*)alloc((size_t)4*3*BB*64*4);      // [slot][l][b][64]
  float* ubuf = (float*)alloc((size_t)4*2*BB*64*4);      // [slot][j][b][64]
  float* whb1 = (float*)alloc((size_t)2*BB*2048*4);      // Wh1*h1 ring [2][b][2048]
  float* whb2 = (float*)alloc((size_t)2*BB*2048*4);      // Wh2*h2 ring [2][b][2048]
  float* cbuf = (float*)alloc((size_t)3*BB*DD*4);
  float* dbuf = (float*)alloc((size_t)3*BB*KK*4);
  float* biasg= (float*)alloc((size_t)3*2048*4);
  float* dump = (float*)alloc((size_t)BB*128*4);         // pad-column sink
  if (used > ws_size) { fprintf(stderr, "ws too small: need %zu have %zu\n", used, ws_size); return; }

  const long SZG = (long)BB*2048;
  const long SZR = (long)BB*64;

  auto slotg = [&](int s, int l){ return accg + (long)((s&3)*3+l)*SZG; };
  auto slotr = [&](int s, int l){ return accr + (long)((s&3)*3+l)*SZR; };
  auto slotu = [&](int s, int j){ return ubuf + (long)((s&3)*2+j)*SZR; };
  auto slotw1= [&](int s){ return whb1 + (long)(s&1)*SZG; };
  auto slotw2= [&](int s){ return whb2 + (long)(s&1)*SZG; };

  // ---- setup
  {
    long tot = (long)TT*BB*CC;
    k_xconv<<<dim3((tot + 255)/256), 256, 0, stream>>>(inputs, xb);
  }
  // zero padded weight buffers (pad rows must be 0; ws is poisoned 0xAA)
  hipMemsetAsync(BXT,  0, (size_t)6400*512*2, stream);
  hipMemsetAsync(BG0T, 0, (size_t)6400*512*2, stream);
  hipMemsetAsync(BG1T, 0, (size_t)4352*512*2, stream);

  auto tp = [&](const float* src, long row_off, long srow, bf16* dstbase, long colbase, int N, int K){
    long total = (long)N*K;
    k_tpose<<<dim3((total + 255)/256), 256, 0, stream>>>(src + row_off*srow, srow, dstbase + colbase*K, K, total);
  };
  // BXT cols: [Wx0|Wr0|Wx1|Wr1|Wx2|Wr2|pad]
  tp(wx_w[0],0,2048, BXT,0,2048,512);   tp(wr_w[0],0,64, BXT,2048,64,512);
  tp(wx_w[1],0,2048, BXT,2112,2048,512);tp(wr_w[1],0,64, BXT,4160,64,512);
  tp(wx_w[2],0,2048, BXT,4224,2048,512);tp(wr_w[2],0,64, BXT,6272,64,512);
  // BG0T cols: [Wx1.h0|Wr1.h0|Wx2.h0|Wr2.h0|Wh0|Wl0|pad]
  tp(wx_w[1],512,2048, BG0T,0,2048,512);   tp(wr_w[1],512,64, BG0T,2048,64,512);
  tp(wx_w[2],512,2048, BG0T,2112,2048,512);tp(wr_w[2],512,64, BG0T,4160,64,512);
  tp(wh_w[0],0,2048,   BG0T,4224,2048,512);tp(wl_w[0],0,64,   BG0T,6272,64,512);
  // BG1T cols: [Wx2.h1|Wr2.h1|Wh1|Wl1|pad]
  tp(wx_w[2],1024,2048, BG1T,0,2048,512);  tp(wr_w[2],1024,64, BG1T,2048,64,512);
  tp(wh_w[1],0,2048,    BG1T,2112,2048,512);tp(wl_w[1],0,64,   BG1T,4160,64,512);
  // BG2T: [Wh2]
  tp(wh_w[2],0,2048, BG2T,0,2048,512);
  // projT
  tp(proj_w,0,512, projT,0,512,1536);

  k_bias<<<dim3(24),256,0,stream>>>(wx_b[0],wh_b[0],wx_b[1],wh_b[1],wx_b[2],wh_b[2], biasg);
  hipMemsetAsync(ubuf, 0, (size_t)4*2*BB*64*4, stream);
  hipMemsetAsync(whb1, 0, (size_t)2*SZG*4, stream);
  hipMemsetAsync(whb2, 0, (size_t)2*SZG*4, stream);
  hipMemsetAsync(cbuf, 0, (size_t)3*BB*DD*4, stream);
  k_dinit<<<dim3((3*BB*KK + 255)/256),256,0,stream>>>(init_keys, dbuf);

  // ---- pipelined recurrence: A(t) = {E0(t),E1(t-1),E2(t-2)}, B(t) = {I(t+2),G0(t),G1(t-1),G2(t-2)}
  for (int t = -2; t <= TT + 1; ++t) {
    // ----- A phase
    CArgs ca{}; ca.n = 0;
    auto addE = [&](int s, int l){
      CellDesc& e = ca.e[ca.n++];
      e.gate = slotg(s,l);
      e.gate2 = (l==1) ? slotw1(s) : (l==2) ? slotw2(s) : nullptr;
      e.gr = slotr(s,l);
      e.u0 = (l>=1) ? slotu(s-1,0) : nullptr;
      e.u1 = (l>=2) ? slotu(s-1,1) : nullptr;
      e.c = cbuf + (long)l*BB*DD; e.d = dbuf + (long)l*BB*KK;
      e.hout = Hall + (long)s*1536 + (long)l*512;
    };
    if (t   >= 0 && t   < TT) addE(t,   0);
    if (t-1 >= 0 && t-1 < TT) addE(t-1, 1);
    if (t-2 >= 0 && t-2 < TT) addE(t-2, 2);
    if (ca.n)
      cell_batched<<<dim3(64, ca.n), 256, 0, stream>>>(ca, wd_w);

    // ----- B phase
    GArgs ga{}; ga.ng = 0; ga.K = 512;
    int cursor = 0;
    auto addG = [&](const bf16* A, long lda, const bf16* Bm, int Npad, SegList sl){
      GDesc& g = ga.g[ga.ng++];
      g.A = A; g.lda = lda; g.B = Bm; g.ldb = 512;
      g.mtiles = 8; g.ntiles = Npad/128; g.tile_beg = cursor; g.order = 1;
      cursor += g.mtiles * g.ntiles;
      g.segs = sl;
    };
    if (t+2 >= 0 && t+2 < TT) {  // I(t+2): stores + bias
      int s = t+2;
      SegList sl{}; sl.n = 7;
      sl.s[0] = { slotg(s,0), 2048,    0, 0, biasg + 0    };
      sl.s[1] = { slotr(s,0),   64, 2048, 0, nullptr      };
      sl.s[2] = { slotg(s,1), 2048, 2112, 0, biasg + 2048 };
      sl.s[3] = { slotr(s,1),   64, 4160, 0, nullptr      };
      sl.s[4] = { slotg(s,2), 2048, 4224, 0, biasg + 4096 };
      sl.s[5] = { slotr(s,2),   64, 6272, 0, nullptr      };
      sl.s[6] = { dump,        128, 6336, 0, nullptr      };
      addG(xb + (long)s*BB*CC, 512, BXT, 6400, sl);
    }
    if (t >= 0 && t < TT) {      // G0(t): plain += (single writer per launch)
      int s = t;
      SegList sl{}; sl.n = 7;
      sl.s[0] = { slotg(s,1),   2048,    0, 1, nullptr };
      sl.s[1] = { slotr(s,1),     64, 2048, 1, nullptr };
      sl.s[2] = { slotg(s,2),   2048, 2112, 1, nullptr };
      sl.s[3] = { slotr(s,2),     64, 4160, 1, nullptr };
      sl.s[4] = { slotg(s+1,0), 2048, 4224, 1, nullptr };  // Wh0 -> gate0(t+1)
      sl.s[5] = { slotu(s,0),     64, 6272, 0, nullptr };  // u0 = h0@Wl0
      sl.s[6] = { dump,          128, 6336, 0, nullptr };
      addG(Hall + (long)s*1536, LDH, BG0T, 6400, sl);
    }
    if (t-1 >= 0 && t-1 < TT) {  // G1(t-1)
      int s = t-1;
      SegList sl{}; sl.n = 5;
      sl.s[0] = { slotg(s,2),   2048,    0, 1, nullptr };
      sl.s[1] = { slotr(s,2),     64, 2048, 1, nullptr };
      sl.s[2] = { slotw1(s+1),  2048, 2112, 0, nullptr };  // Wh1*h1(s) -> whb1 ring (store)
      sl.s[3] = { slotu(s,1),     64, 4160, 0, nullptr };  // u1 = h1@Wl1
      sl.s[4] = { dump,          128, 4224, 0, nullptr };
      addG(Hall + (long)s*1536 + 512, LDH, BG1T, 4352, sl);
    }
    if (t-2 >= 0 && t-2 <= TT-2) {  // G2(t-2): pure store into whb2 ring
      int s = t-2;
      SegList sl{}; sl.n = 1;
      sl.s[0] = { slotw2(s+1), 2048, 0, 0, nullptr };      // Wh2*h2(s) -> whb2 ring
      addG(Hall + (long)s*1536 + 1024, LDH, BG2T, 2048, sl);
    }
    if (cursor) {
      ga.total = cursor; ga.chunk = (cursor + 7) / 8;
      gemm_batched<<<dim3(ga.chunk * 8), 256, 0, stream>>>(ga);
    }
  }

  // ---- projection: out[b][t][:] = Hall[b][t][:] @ proj + proj_b
  {
    GArgs ga{}; ga.ng = 1; ga.K = 1536;
    GDesc& g = ga.g[0];
    g.A = Hall; g.lda = 1536; g.B = projT; g.ldb = 1536;
    g.mtiles = (BB*TT)/64; g.ntiles = 512/128; g.tile_beg = 0; g.order = 0;
    g.segs.n = 1;
    g.segs.s[0] = { out, 512, 0, 0, proj_b };
    ga.total = g.mtiles * g.ntiles; ga.chunk = (ga.total + 7) / 8;
    gemm_batched<<<dim3(ga.chunk * 8), 256, 0, stream>>>(ga);
  }
}

// Round 5
// 3286.294 us; speedup vs baseline: 1.2901x; 1.0313x over previous
//
#include <hip/hip_runtime.h>
#include <hip/hip_bf16.h>
#include <cstdio>

typedef __hip_bfloat16 bf16;
typedef __attribute__((ext_vector_type(8))) short s16x8;
typedef __attribute__((ext_vector_type(4))) float f32x4;

// Problem constants
#define TT 55
#define BB 512
#define CC 512
#define DD 512
#define KK 64
#define LDH ((long)TT*1536)
#define XW 6400L   // XGR row width

typedef const __attribute__((address_space(1))) unsigned int gu32;
typedef __attribute__((address_space(3))) unsigned int lu32;
__device__ __forceinline__ void gload16(const void* g, void* l) {
  __builtin_amdgcn_global_load_lds((gu32*)g, (lu32*)l, 16, 0, 0);
}

struct Seg {
  void*  dst;          // destination base (float* or bf16* per mode)
  long   ldd;          // row stride (elements)
  int    col_begin;    // inclusive (GEMM N space), 64-aligned, sorted asc
  int    mode;         // 0 = f32 store (+bias), 1 = f32 +=, 2 = bf16 store (+bias)
  const float* bias;   // indexed by (col - col_begin), may be null
};
struct SegList { Seg s[8]; int n; };

struct GDesc {
  const bf16* A; const bf16* B;
  long lda, ldb;
  int mtiles, ntiles, tile_beg, order;  // 0=nt-fast, 1=mt-fast, 2=banded(32 mt x all nt)
  SegList segs;
};
struct GArgs { GDesc g[4]; int ng; int K; int total; int chunk; };

// ---------------- batched GEMM: C[seg] (+)= A[MxK] * B^T[NxK], bf16 in, fp32 acc
// 64x128 tile (MxN), BK=64, 4 waves (2x2 of 32x64), global_load_lds staging with
// XOR-swizzled LDS layout (block p of row r holds global block p^(r&7)) to kill
// the 16-way ds_read_b128 bank conflicts of the unpadded [r][64] layout.
__global__ __launch_bounds__(256) void gemm_batched(GArgs args)
{
  __shared__ __align__(16) bf16 As[64][64];    // 8 KB
  __shared__ __align__(16) bf16 Bs[128][64];   // 16 KB

  // XCD-aware: bid%8 ~ XCD; each XCD gets a contiguous tile chunk.
  int tile = (int)(blockIdx.x & 7) * args.chunk + (int)(blockIdx.x >> 3);
  if (tile >= args.total) return;

  int gi = 0;
  if (args.ng > 1 && tile >= args.g[1].tile_beg) gi = 1;
  if (args.ng > 2 && tile >= args.g[2].tile_beg) gi = 2;
  if (args.ng > 3 && tile >= args.g[3].tile_beg) gi = 3;
  const GDesc& g = args.g[gi];
  const int local = tile - g.tile_beg;
  int mt, nt;
  if (g.order == 1)      { mt = local % g.mtiles; nt = local / g.mtiles; }
  else if (g.order == 2) { int band = local / (32*g.ntiles); int rem = local % (32*g.ntiles);
                           nt = rem % g.ntiles; mt = band*32 + rem / g.ntiles; }
  else                   { nt = local % g.ntiles; mt = local / g.ntiles; }

  const int tid  = threadIdx.x;
  const int wave = tid >> 6, lane = tid & 63;
  const int q = lane >> 4, mm = lane & 15;
  const int s7 = mm & 7;
  const int wm = wave >> 1, wn = wave & 1;
  const long m0 = (long)mt * 64;
  const long n0 = (long)nt * 128;

  const bf16* Ab = g.A + m0 * g.lda;
  const bf16* Bb = g.B + n0 * g.ldb;
  const long lda = g.lda, ldb = g.ldb;
  const int l8 = lane >> 3;                 // row within 8-row staging group
  const int gc = ((lane & 7) ^ l8) << 3;    // swizzled global col (elements)

  f32x4 acc[2][4] = {};

  for (int k0 = 0; k0 < args.K; k0 += 64) {
#pragma unroll
    for (int p = 0; p < 2; ++p) {
      int r = p*32 + wave*8;
      gload16(Ab + (long)(r + l8)*lda + k0 + gc, &As[r][0]);
    }
#pragma unroll
    for (int p = 0; p < 4; ++p) {
      int r = p*32 + wave*8;
      gload16(Bb + (long)(r + l8)*ldb + k0 + gc, &Bs[r][0]);
    }
    __syncthreads();
#pragma unroll
    for (int kk = 0; kk < 64; kk += 32) {
      const int pc = ((((kk >> 3) + q) ^ s7) << 3);  // physical col of logical kk+q*8
      s16x8 av[2], bv[4];
#pragma unroll
      for (int i = 0; i < 2; ++i) av[i] = *(const s16x8*)&As[wm*32 + i*16 + mm][pc];
#pragma unroll
      for (int j = 0; j < 4; ++j) bv[j] = *(const s16x8*)&Bs[wn*64 + j*16 + mm][pc];
#pragma unroll
      for (int i = 0; i < 2; ++i)
#pragma unroll
        for (int j = 0; j < 4; ++j)
          acc[i][j] = __builtin_amdgcn_mfma_f32_16x16x32_bf16(av[i], bv[j], acc[i][j], 0,0,0);
    }
    __syncthreads();
  }

  // epilogue: segment lookup per 16-col group (boundaries are 64-aligned)
#pragma unroll
  for (int j = 0; j < 4; ++j) {
    int colbase = (int)n0 + wn*64 + j*16;
    Seg sg = g.segs.s[0];
    for (int i = 1; i < g.segs.n; ++i)
      if (colbase >= g.segs.s[i].col_begin) sg = g.segs.s[i];
    int dcol = colbase + mm - sg.col_begin;
    float bv = sg.bias ? sg.bias[dcol] : 0.0f;
#pragma unroll
    for (int i = 0; i < 2; ++i) {
      f32x4 a = acc[i][j];
#pragma unroll
      for (int r = 0; r < 4; ++r) {
        long row = m0 + wm*32 + i*16 + q*4 + r;  // C/D: col=lane&15, row=q*4+reg
        long off = row * sg.ldd + dcol;
        if (sg.mode == 1)      ((float*)sg.dst)[off] += a[r];
        else if (sg.mode == 2) ((bf16*)sg.dst)[off] = __float2bfloat16(a[r] + bv);
        else                   ((float*)sg.dst)[off] = a[r] + bv;
      }
    }
  }
}

// ---------------- batched cell update: up to 3 independent (step,layer) cells
struct CellDesc {
  const void* xg;      // x-driven gate part (row stride XW), may be null
  const void* xr;      // x-driven gr part (row stride XW), may be null
  int xbf;             // 1 = xg/xr are bf16, 0 = fp32
  const float* gate;   // fp32 ring [512][2048]
  const float* gate2;  // extra addend (whb ring), may be null
  const float* gr;     // fp32 [512][64], may be null
  const float* u0;     // may be null
  const float* u1;     // may be null
  float* c;            // [512][512]
  float* d;            // [512][64]
  bf16*  hout;         // row stride LDH
};
struct CArgs { CellDesc e[3]; int n; };

__device__ inline float sigm(float x){ return 1.0f/(1.0f + __expf(-x)); }

__global__ __launch_bounds__(256) void cell_batched(CArgs a, const float* __restrict__ wd)
{
  const CellDesc e = a.e[blockIdx.y];
  const int tid = threadIdx.x;
  const int r0 = blockIdx.x * 8;   // 8 batch rows per block, grid.x = 64
  __shared__ float dn[8][64];

  for (int i = tid; i < 512; i += 256) {
    int r = i >> 6, k = i & 63;
    long row = r0 + r;
    float gv = 0.0f;
    if (e.xr) gv += e.xbf ? __bfloat162float(((const bf16*)e.xr)[row*XW + k])
                          : ((const float*)e.xr)[row*XW + k];
    if (e.gr) gv += e.gr[row*64 + k];
    if (e.u0) gv += (1.0f/3.0f)*e.u0[row*64 + k];
    if (e.u1) gv += (1.0f/3.0f)*e.u1[row*64 + k];
    float rr = sigm(gv);
    float dv = rr * e.d[row*64 + k];
    e.d[row*64 + k] = dv;
    dn[r][k] = dv;
  }
  __syncthreads();

  float accv[2][8] = {};
  for (int k = 0; k < 64; ++k) {
    float w0 = wd[k*512 + tid];
    float w1 = wd[k*512 + tid + 256];
#pragma unroll
    for (int r = 0; r < 8; ++r) {
      float dv = dn[r][k];
      accv[0][r] += dv * w0;
      accv[1][r] += dv * w1;
    }
  }

#pragma unroll
  for (int half = 0; half < 2; ++half) {
    int n = tid + half*256;
#pragma unroll
    for (int r = 0; r < 8; ++r) {
      long row = r0 + r;
      const float* gg = e.gate + row*2048;
      float fv = gg[n], iv = gg[512+n], ov = gg[1024+n], cb = gg[1536+n];
      if (e.gate2) {
        const float* g2 = e.gate2 + row*2048;
        fv += g2[n]; iv += g2[512+n]; ov += g2[1024+n]; cb += g2[1536+n];
      }
      if (e.xg) {
        if (e.xbf) {
          const bf16* xg = (const bf16*)e.xg + row*XW;
          fv += __bfloat162float(xg[n]);      iv += __bfloat162float(xg[512+n]);
          ov += __bfloat162float(xg[1024+n]); cb += __bfloat162float(xg[1536+n]);
        } else {
          const float* xg = (const float*)e.xg + row*XW;
          fv += xg[n]; iv += xg[512+n]; ov += xg[1024+n]; cb += xg[1536+n];
        }
      }
      fv = sigm(fv); iv = sigm(iv); ov = sigm(ov); cb = tanhf(cb);
      float cv = fv * e.c[row*512 + n] + iv * cb + tanhf(accv[half][r]);
      e.c[row*512 + n] = cv;
      e.hout[row*LDH + n] = __float2bfloat16(ov * tanhf(cv));
    }
  }
}

// ---------------- setup kernels
__global__ void k_tpose(const float* __restrict__ src, long srow,
                        bf16* __restrict__ dst, int K, long total)
{
  long idx = (long)blockIdx.x * 256 + threadIdx.x;
  if (idx >= total) return;
  long n = idx / K;
  long k = idx - n * K;
  dst[idx] = __float2bfloat16(src[k * srow + n]);
}

__global__ void k_xconv(const float* __restrict__ x, bf16* __restrict__ xb)
{
  long i = (long)blockIdx.x * 256 + threadIdx.x;
  if (i >= (long)TT*BB*CC) return;
  int cc = (int)(i & 511);
  long r = i >> 9;
  int t = (int)(r / BB), b = (int)(r - (long)t*BB);
  xb[i] = __float2bfloat16(x[((long)b*TT + t)*CC + cc]);
}

__global__ void k_bias(const float* b0,const float* b1,const float* b2,
                       const float* b3,const float* b4,const float* b5,
                       float* out)
{
  int i = blockIdx.x*256 + threadIdx.x;
  if (i < 2048)      out[i] = b0[i] + b1[i];
  else if (i < 4096) out[i] = b2[i-2048] + b3[i-2048];
  else if (i < 6144) out[i] = b4[i-4096] + b5[i-4096];
}

__global__ void k_dinit(const float* __restrict__ keys, float* __restrict__ d)
{
  int i = blockIdx.x*256 + threadIdx.x;
  if (i < 3*BB*KK) d[i] = keys[i % (BB*KK)];
}

// ---------------- host
extern "C" void kernel_launch(void* const* d_in, const int* in_sizes, int n_in,
                              void* d_out, int out_size, void* d_ws, size_t ws_size,
                              hipStream_t stream)
{
  const float* inputs    = (const float*)d_in[0];
  const float* init_keys = (const float*)d_in[1];
  const float* wx_w[3] = {(const float*)d_in[2],  (const float*)d_in[8],  (const float*)d_in[14]};
  const float* wx_b[3] = {(const float*)d_in[3],  (const float*)d_in[9],  (const float*)d_in[15]};
  const float* wh_w[3] = {(const float*)d_in[4],  (const float*)d_in[10], (const float*)d_in[16]};
  const float* wh_b[3] = {(const float*)d_in[5],  (const float*)d_in[11], (const float*)d_in[17]};
  const float* wr_w[3] = {(const float*)d_in[6],  (const float*)d_in[12], (const float*)d_in[18]};
  const float* wl_w[3] = {(const float*)d_in[7],  (const float*)d_in[13], (const float*)d_in[19]};
  const float* wd_w   = (const float*)d_in[20];
  const float* proj_w = (const float*)d_in[21];
  const float* proj_b = (const float*)d_in[22];
  float* out = (float*)d_out;

  char* wsp = (char*)d_ws;
  size_t used = 0;
  auto alloc = [&](size_t bytes) {
    char* p = wsp + used;
    used += (bytes + 255) & ~(size_t)255;
    return p;
  };
  bf16* xb    = (bf16*)alloc((size_t)TT*BB*CC*2);        // [t][b][c] = [28160][512]
  bf16* BXT   = (bf16*)alloc((size_t)6400*512*2);        // x-driven  B^T (padded)
  bf16* BG0T  = (bf16*)alloc((size_t)6400*512*2);        // h0-driven B^T (padded)
  bf16* BG1T  = (bf16*)alloc((size_t)4352*512*2);        // h1-driven B^T (padded)
  bf16* BG2T  = (bf16*)alloc((size_t)2048*512*2);        // h2-driven B^T
  bf16* projT = (bf16*)alloc((size_t)512*1536*2);
  bf16* Hall  = (bf16*)alloc((size_t)BB*TT*1536*2);      // [b][t][3*512]
  float* accg = (float*)alloc((size_t)4*3*BB*2048*4);    // [slot][l][b][2048]
  float* accr = (float*)alloc((size_t)4*3*BB*64*4);      // [slot][l][b][64]
  float* ubuf = (float*)alloc((size_t)4*2*BB*64*4);      // [slot][j][b][64]
  float* whb1 = (float*)alloc((size_t)2*BB*2048*4);      // Wh1*h1 ring
  float* whb2 = (float*)alloc((size_t)2*BB*2048*4);      // Wh2*h2 ring
  float* cbuf = (float*)alloc((size_t)3*BB*DD*4);
  float* dbuf = (float*)alloc((size_t)3*BB*KK*4);
  float* biasg= (float*)alloc((size_t)3*2048*4);
  float* dump = (float*)alloc((size_t)BB*128*4);         // pad-column sink (in-loop, M=512)

  // plan: 0 = fp32 XGR precompute, 1 = bf16 XGR precompute, 2 = fallback (I in loop)
  const size_t xgr32 = (size_t)TT*BB*XW*4, xgr16 = (size_t)TT*BB*XW*2;
  int plan; char* xgrp = nullptr;
  if      (used + xgr32 <= ws_size) { plan = 0; xgrp = alloc(xgr32); }
  else if (used + xgr16 <= ws_size) { plan = 1; xgrp = alloc(xgr16); }
  else                              { plan = 2; }
  if (used > ws_size) return;

  const long SZG = (long)BB*2048;
  const long SZR = (long)BB*64;

  auto slotg = [&](int s, int l){ return accg + (long)((s&3)*3+l)*SZG; };
  auto slotr = [&](int s, int l){ return accr + (long)((s&3)*3+l)*SZR; };
  auto slotu = [&](int s, int j){ return ubuf + (long)((s&3)*2+j)*SZR; };
  auto slotw1= [&](int s){ return whb1 + (long)(s&1)*SZG; };
  auto slotw2= [&](int s){ return whb2 + (long)(s&1)*SZG; };
  auto xat   = [&](long col)->void* {
    return plan==0 ? (void*)((float*)xgrp + col) : (void*)((bf16*)xgrp + col);
  };

  // ---- setup
  {
    long tot = (long)TT*BB*CC;
    k_xconv<<<dim3((tot + 255)/256), 256, 0, stream>>>(inputs, xb);
  }
  hipMemsetAsync(BXT,  0, (size_t)6400*512*2, stream);
  hipMemsetAsync(BG0T, 0, (size_t)6400*512*2, stream);
  hipMemsetAsync(BG1T, 0, (size_t)4352*512*2, stream);

  auto tp = [&](const float* src, long row_off, long srow, bf16* dstbase, long colbase, int N, int K){
    long total = (long)N*K;
    k_tpose<<<dim3((total + 255)/256), 256, 0, stream>>>(src + row_off*srow, srow, dstbase + colbase*K, K, total);
  };
  // BXT cols: [Wx0|Wr0|Wx1|Wr1|Wx2|Wr2|pad]
  tp(wx_w[0],0,2048, BXT,0,2048,512);   tp(wr_w[0],0,64, BXT,2048,64,512);
  tp(wx_w[1],0,2048, BXT,2112,2048,512);tp(wr_w[1],0,64, BXT,4160,64,512);
  tp(wx_w[2],0,2048, BXT,4224,2048,512);tp(wr_w[2],0,64, BXT,6272,64,512);
  // BG0T cols: [Wx1.h0|Wr1.h0|Wx2.h0|Wr2.h0|Wh0|Wl0|pad]
  tp(wx_w[1],512,2048, BG0T,0,2048,512);   tp(wr_w[1],512,64, BG0T,2048,64,512);
  tp(wx_w[2],512,2048, BG0T,2112,2048,512);tp(wr_w[2],512,64, BG0T,4160,64,512);
  tp(wh_w[0],0,2048,   BG0T,4224,2048,512);tp(wl_w[0],0,64,   BG0T,6272,64,512);
  // BG1T cols: [Wx2.h1|Wr2.h1|Wh1|Wl1|pad]
  tp(wx_w[2],1024,2048, BG1T,0,2048,512);  tp(wr_w[2],1024,64, BG1T,2048,64,512);
  tp(wh_w[1],0,2048,    BG1T,2112,2048,512);tp(wl_w[1],0,64,   BG1T,4160,64,512);
  tp(wh_w[2],0,2048, BG2T,0,2048,512);
  tp(proj_w,0,512, projT,0,512,1536);

  k_bias<<<dim3(24),256,0,stream>>>(wx_b[0],wh_b[0],wx_b[1],wh_b[1],wx_b[2],wh_b[2], biasg);
  hipMemsetAsync(ubuf, 0, (size_t)4*2*BB*64*4, stream);
  hipMemsetAsync(whb1, 0, (size_t)2*SZG*4, stream);
  hipMemsetAsync(whb2, 0, (size_t)2*SZG*4, stream);
  hipMemsetAsync(cbuf, 0, (size_t)3*BB*DD*4, stream);
  hipMemsetAsync(accg, 0, (size_t)SZG*4, stream);   // slotg(0,0): E0(0)'s h-part (h(-1)=0)
  k_dinit<<<dim3((3*BB*KK + 255)/256),256,0,stream>>>(init_keys, dbuf);

  // ---- mega-GEMM: all x-driven parts for all 55 steps (plans 0/1)
  if (plan < 2) {
    GArgs ga{}; ga.ng = 1; ga.K = 512;
    GDesc& g = ga.g[0];
    g.A = xb; g.lda = 512; g.B = BXT; g.ldb = 512;
    g.mtiles = (TT*BB)/64; g.ntiles = 6400/128; g.tile_beg = 0; g.order = 2;
    int md = (plan == 0) ? 0 : 2;
    g.segs.n = 6;
    g.segs.s[0] = { xat(0),    XW,    0, md, biasg + 0    };
    g.segs.s[1] = { xat(2048), XW, 2048, md, nullptr      };
    g.segs.s[2] = { xat(2112), XW, 2112, md, biasg + 2048 };
    g.segs.s[3] = { xat(4160), XW, 4160, md, nullptr      };
    g.segs.s[4] = { xat(4224), XW, 4224, md, biasg + 4096 };
    g.segs.s[5] = { xat(6272), XW, 6272, md, nullptr      };  // covers r2 + pad (contiguous in XGR)
    ga.total = g.mtiles * g.ntiles; ga.chunk = (ga.total + 7) / 8;
    gemm_batched<<<dim3(ga.chunk * 8), 256, 0, stream>>>(ga);
  }

  // ---- pipelined recurrence: A(t) = {E0(t),E1(t-1),E2(t-2)}, B(t) = {[I(t+2)],G0(t),G1(t-1),G2(t-2)}
  for (int t = -2; t <= TT + 1; ++t) {
    // ----- A phase
    CArgs ca{}; ca.n = 0;
    auto addE = [&](int s, int l){
      CellDesc& e = ca.e[ca.n++];
      if (plan < 2) {
        long ro = (long)s*512*XW + (long)l*2112;
        e.xg = xat(0) ? (plan==0 ? (void*)((float*)xgrp + ro) : (void*)((bf16*)xgrp + ro)) : nullptr;
        e.xr = plan==0 ? (void*)((float*)xgrp + ro + 2048) : (void*)((bf16*)xgrp + ro + 2048);
        e.xbf = (plan == 1);
        e.gr = (l >= 1) ? slotr(s,l) : nullptr;
      } else {
        e.xg = nullptr; e.xr = nullptr; e.xbf = 0;
        e.gr = slotr(s,l);
      }
      e.gate = slotg(s,l);
      e.gate2 = (l==1) ? slotw1(s) : (l==2) ? slotw2(s) : nullptr;
      e.u0 = (l>=1) ? slotu(s-1,0) : nullptr;
      e.u1 = (l>=2) ? slotu(s-1,1) : nullptr;
      e.c = cbuf + (long)l*BB*DD; e.d = dbuf + (long)l*BB*KK;
      e.hout = Hall + (long)s*1536 + (long)l*512;
    };
    if (t   >= 0 && t   < TT) addE(t,   0);
    if (t-1 >= 0 && t-1 < TT) addE(t-1, 1);
    if (t-2 >= 0 && t-2 < TT) addE(t-2, 2);
    if (ca.n)
      cell_batched<<<dim3(64, ca.n), 256, 0, stream>>>(ca, wd_w);

    // ----- B phase
    GArgs ga{}; ga.ng = 0; ga.K = 512;
    int cursor = 0;
    auto addG = [&](const bf16* A, long lda, const bf16* Bm, int Npad, SegList sl){
      GDesc& g = ga.g[ga.ng++];
      g.A = A; g.lda = lda; g.B = Bm; g.ldb = 512;
      g.mtiles = 8; g.ntiles = Npad/128; g.tile_beg = cursor; g.order = 1;
      cursor += g.mtiles * g.ntiles;
      g.segs = sl;
    };
    if (plan == 2 && t+2 >= 0 && t+2 < TT) {  // I(t+2): fallback only
      int s = t+2;
      SegList sl{}; sl.n = 7;
      sl.s[0] = { slotg(s,0), 2048,    0, 0, biasg + 0    };
      sl.s[1] = { slotr(s,0),   64, 2048, 0, nullptr      };
      sl.s[2] = { slotg(s,1), 2048, 2112, 0, biasg + 2048 };
      sl.s[3] = { slotr(s,1),   64, 4160, 0, nullptr      };
      sl.s[4] = { slotg(s,2), 2048, 4224, 0, biasg + 4096 };
      sl.s[5] = { slotr(s,2),   64, 6272, 0, nullptr      };
      sl.s[6] = { dump,        128, 6336, 0, nullptr      };
      addG(xb + (long)s*BB*CC, 512, BXT, 6400, sl);
    }
    if (t >= 0 && t < TT) {      // G0(t)
      int s = t;
      int am = (plan < 2) ? 0 : 1;  // precompute: sole writer -> store; fallback: += onto I
      SegList sl{}; sl.n = 7;
      sl.s[0] = { slotg(s,1),   2048,    0, am, nullptr };
      sl.s[1] = { slotr(s,1),     64, 2048, am, nullptr };
      sl.s[2] = { slotg(s,2),   2048, 2112, am, nullptr };
      sl.s[3] = { slotr(s,2),     64, 4160, am, nullptr };
      sl.s[4] = { slotg(s+1,0), 2048, 4224, am, nullptr };  // Wh0 -> gate0(t+1)
      sl.s[5] = { slotu(s,0),     64, 6272, 0,  nullptr };  // u0 = h0@Wl0
      sl.s[6] = { dump,          128, 6336, 0,  nullptr };
      addG(Hall + (long)s*1536, LDH, BG0T, 6400, sl);
    }
    if (t-1 >= 0 && t-1 < TT) {  // G1(t-1)
      int s = t-1;
      SegList sl{}; sl.n = 5;
      sl.s[0] = { slotg(s,2),   2048,    0, 1, nullptr };
      sl.s[1] = { slotr(s,2),     64, 2048, 1, nullptr };
      sl.s[2] = { slotw1(s+1),  2048, 2112, 0, nullptr };  // Wh1*h1(s) -> whb1 ring
      sl.s[3] = { slotu(s,1),     64, 4160, 0, nullptr };  // u1 = h1@Wl1
      sl.s[4] = { dump,          128, 4224, 0, nullptr };
      addG(Hall + (long)s*1536 + 512, LDH, BG1T, 4352, sl);
    }
    if (t-2 >= 0 && t-2 <= TT-2) {  // G2(t-2)
      int s = t-2;
      SegList sl{}; sl.n = 1;
      sl.s[0] = { slotw2(s+1), 2048, 0, 0, nullptr };      // Wh2*h2(s) -> whb2 ring
      addG(Hall + (long)s*1536 + 1024, LDH, BG2T, 2048, sl);
    }
    if (cursor) {
      ga.total = cursor; ga.chunk = (cursor + 7) / 8;
      gemm_batched<<<dim3(ga.chunk * 8), 256, 0, stream>>>(ga);
    }
  }

  // ---- projection: out[b][t][:] = Hall[b][t][:] @ proj + proj_b
  {
    GArgs ga{}; ga.ng = 1; ga.K = 1536;
    GDesc& g = ga.g[0];
    g.A = Hall; g.lda = 1536; g.B = projT; g.ldb = 1536;
    g.mtiles = (BB*TT)/64; g.ntiles = 512/128; g.tile_beg = 0; g.order = 2;
    g.segs.n = 1;
    g.segs.s[0] = { out, 512, 0, 0, proj_b };
    ga.total = g.mtiles * g.ntiles; ga.chunk = (ga.total + 7) / 8;
    gemm_batched<<<dim3(ga.chunk * 8), 256, 0, stream>>>(ga);
  }
}